// Round 13
// baseline (2009.060 us; speedup 1.0000x reference)
//
#include <hip/hip_runtime.h>
#include <math.h>

#define HID 256
#define II 512
#define SS 16
#define RR 16
#define KC 4
#define NLAY 8
#define BATCH 16
#define LSEQ 2048
#define EPSV 1e-5f
#define NCCH 64
#define LCH (LSEQ/NCCH)   // 32
#define CSTR 130          // GEMM LDS epilogue row stride (ushorts)

typedef __attribute__((ext_vector_type(8))) short bf16x8;
typedef __attribute__((ext_vector_type(4))) float f32x4;
typedef __attribute__((ext_vector_type(2))) float f32x2;

#define GLOAD16(gp, lp) __builtin_amdgcn_global_load_lds( \
    (const __attribute__((address_space(1))) unsigned int*)(gp), \
    (__attribute__((address_space(3))) unsigned int*)(lp), 16, 0, 0)

__device__ __forceinline__ float silu_f(float x) { return x / (1.f + __expf(-x)); }
__device__ __forceinline__ float bf2f(unsigned short u) {
    union { unsigned int i; float f; } v; v.i = (unsigned int)u << 16; return v.f;
}
__device__ __forceinline__ unsigned short f2bf(float f) {
    union { float f; unsigned int i; } v; v.f = f;
    unsigned int r = v.i + 0x7FFFu + ((v.i >> 16) & 1u);
    return (unsigned short)(r >> 16);
}
// scalar pow tree (slow-path + Pr)
__device__ __forceinline__ void powtree(float r, float* pw) {
    pw[0] = r; pw[1] = r * r; pw[3] = pw[1] * pw[1];
    pw[7] = pw[3] * pw[3]; pw[15] = pw[7] * pw[7];
    pw[2] = pw[1] * pw[0]; pw[4] = pw[3] * pw[0]; pw[5] = pw[3] * pw[1];
    pw[6] = pw[3] * pw[2]; pw[8] = pw[7] * pw[0]; pw[9] = pw[7] * pw[1];
    pw[10] = pw[7] * pw[2]; pw[11] = pw[7] * pw[3]; pw[12] = pw[7] * pw[4];
    pw[13] = pw[7] * pw[5]; pw[14] = pw[7] * pw[6];
}
// packed pow tree: pw2[k] = {r^(2k+1), r^(2k+2)}, 3 scalar + 7 packed muls, depth 4
__device__ __forceinline__ void powtree2(float r, f32x2* pw) {
    float r2 = r * r;
    float r4 = r2 * r2;
    float r8 = r4 * r4;
    pw[0] = (f32x2){r, r2};
    pw[1] = pw[0] * r2;
    pw[2] = pw[0] * r4;
    pw[3] = pw[1] * r4;
    pw[4] = pw[0] * r8;
    pw[5] = pw[1] * r8;
    pw[6] = pw[2] * r8;
    pw[7] = pw[3] * r8;
}

// ---------------- f32 -> bf16 weight conversion ----------------
__global__ __launch_bounds__(256) void k_f2bf(const float* __restrict__ in,
                                              unsigned short* __restrict__ out, int n)
{
    for (int i = blockIdx.x * 256 + threadIdx.x; i < n; i += gridDim.x * 256)
        out[i] = f2bf(in[i]);
}

// ---------------- RMSNorm -> bf16 ----------------
__global__ __launch_bounds__(256) void k_rmsnorm(const float* __restrict__ x,
                                                 const float* __restrict__ w,
                                                 unsigned short* __restrict__ out)
{
    int wave = threadIdx.x >> 6;
    int lane = threadIdx.x & 63;
    int row  = blockIdx.x * 4 + wave;
    const float* xr = x + (size_t)row * HID;
    float4 v = *(const float4*)(xr + lane * 4);
    float ss = v.x*v.x + v.y*v.y + v.z*v.z + v.w*v.w;
#pragma unroll
    for (int off = 32; off >= 1; off >>= 1) ss += __shfl_xor(ss, off, 64);
    float inv = 1.0f / sqrtf(ss * (1.0f / (float)HID) + EPSV);
    float4 wv = *(const float4*)(w + lane * 4);
    ushort4 o;
    o.x = f2bf(v.x * inv * wv.x); o.y = f2bf(v.y * inv * wv.y);
    o.z = f2bf(v.z * inv * wv.z); o.w = f2bf(v.w * inv * wv.w);
    *(ushort4*)(out + (size_t)row * HID + lane * 4) = o;
}

// ---------------- bf16 MFMA GEMM (m97 structure) ----------------
template<int RESID, int OUTBF>
__global__ __launch_bounds__(256) void k_gemm_mfma(const unsigned short* __restrict__ A,
                                                   const unsigned short* __restrict__ Bw,
                                                   const float* __restrict__ resid,
                                                   void* __restrict__ Cout,
                                                   int N, int K, int lda, int ntn)
{
    __shared__ unsigned short smem[16640];
    unsigned short* As = smem;
    unsigned short* Bs = smem + 8192;

    int ntm = gridDim.x / ntn;
    int mpx = ntm >> 3;
    int bid = blockIdx.x;
    int xcd = bid & 7, jj0 = bid >> 3;
    int mt = xcd * mpx + (jj0 % mpx);
    int nt = jj0 / mpx;
    int bm = mt * 128, bn = nt * 128;

    int tid = threadIdx.x;
    int wave = tid >> 6, lane = tid & 63;
    int wr = wave >> 1, wc = wave & 1;

    f32x4 acc[4][4];
#pragma unroll
    for (int mi = 0; mi < 4; mi++)
#pragma unroll
        for (int ni = 0; ni < 4; ni++) acc[mi][ni] = (f32x4){0.f, 0.f, 0.f, 0.f};

    int grp0 = wave * 4;
    int rr = lane >> 3, sl = lane & 7;
    int r = lane & 15, ks = lane >> 4;

    for (int k0 = 0; k0 < K; k0 += 64) {
        __syncthreads();
#pragma unroll
        for (int j = 0; j < 4; j++) {
            int g = grp0 + j;
            int row = g * 8 + rr;
            int ss = sl ^ (row & 7);
            GLOAD16(A + (size_t)(bm + row) * lda + k0 + ss * 8, As + g * 512);
            int br = bn + row; if (br > N - 1) br = N - 1;
            GLOAD16(Bw + (size_t)br * K + k0 + ss * 8, Bs + g * 512);
        }
        __syncthreads();
#pragma unroll
        for (int kk = 0; kk < 2; kk++) {
            bf16x8 af[4], bfv[4];
#pragma unroll
            for (int mi = 0; mi < 4; mi++) {
                int row = wr * 64 + mi * 16 + r;
                int boff = row * 128 + (((kk * 4 + ks) ^ (row & 7)) << 4);
                af[mi] = *(const bf16x8*)((const char*)As + boff);
            }
#pragma unroll
            for (int ni = 0; ni < 4; ni++) {
                int row = wc * 64 + ni * 16 + r;
                int boff = row * 128 + (((kk * 4 + ks) ^ (row & 7)) << 4);
                bfv[ni] = *(const bf16x8*)((const char*)Bs + boff);
            }
#pragma unroll
            for (int mi = 0; mi < 4; mi++)
#pragma unroll
                for (int ni = 0; ni < 4; ni++)
                    acc[mi][ni] = __builtin_amdgcn_mfma_f32_16x16x32_bf16(
                        af[mi], bfv[ni], acc[mi][ni], 0, 0, 0);
        }
    }

    int ccol = lane & 15, crow0 = (lane >> 4) * 4;
    if (OUTBF) {
        __syncthreads();
        unsigned short* Cs = smem;
#pragma unroll
        for (int mi = 0; mi < 4; mi++)
#pragma unroll
            for (int ni = 0; ni < 4; ni++) {
                int row = wr * 64 + mi * 16 + crow0;
                int col = wc * 64 + ni * 16 + ccol;
#pragma unroll
                for (int j = 0; j < 4; j++)
                    Cs[(row + j) * CSTR + col] = f2bf(acc[mi][ni][j]);
            }
        __syncthreads();
#pragma unroll
        for (int it = 0; it < 8; it++) {
            int idx = it * 256 + tid;
            int row = idx >> 4, ch = idx & 15;
            uint4 v = *(const uint4*)(Cs + row * CSTR + ch * 8);
            *(uint4*)((unsigned short*)Cout + (size_t)(bm + row) * N + bn + ch * 8) = v;
        }
    } else {
#pragma unroll
        for (int mi = 0; mi < 4; mi++)
#pragma unroll
            for (int ni = 0; ni < 4; ni++) {
                int gc = bn + wc * 64 + ni * 16 + ccol;
                if (gc < N) {
#pragma unroll
                    for (int j = 0; j < 4; j++) {
                        int gr = bm + wr * 64 + mi * 16 + crow0 + j;
                        float v = acc[mi][ni][j];
                        size_t off = (size_t)gr * N + gc;
                        if (RESID) v += resid[off];
                        ((float*)Cout)[off] = v;
                    }
                }
            }
    }
}

// ---------------- depthwise causal conv (K=4) + bias + SiLU ----------------
__global__ __launch_bounds__(256) void k_conv_silu(const unsigned short* __restrict__ proj,
                                                   const float* __restrict__ cw,
                                                   const float* __restrict__ cb,
                                                   unsigned short* __restrict__ u)
{
    __shared__ float sm[11][256];
    int tx = threadIdx.x;
    int t0 = blockIdx.x * 8;
    int i  = blockIdx.y * 256 + tx;
    int b  = blockIdx.z;
#pragma unroll
    for (int r = 0; r < 11; r++) {
        int t = t0 - 3 + r;
        float val = 0.f;
        if (t >= 0) val = bf2f(proj[(size_t)(b * LSEQ + t) * 1024 + i]);
        sm[r][tx] = val;
    }
    __syncthreads();
    float w0 = cw[i * KC + 0], w1 = cw[i * KC + 1], w2 = cw[i * KC + 2], w3 = cw[i * KC + 3];
    float bias = cb[i];
#pragma unroll
    for (int r = 0; r < 8; r++) {
        float s = sm[r][tx] * w0 + sm[r+1][tx] * w1 + sm[r+2][tx] * w2 + sm[r+3][tx] * w3 + bias;
        u[(size_t)(b * LSEQ + t0 + r) * II + i] = f2bf(silu_f(s));
    }
}

// detect A[i,s] == -(s+1) (reference init) -> pow-chain fast path
__device__ __forceinline__ bool a_is_integer(const float* alog, int i) {
    bool fast = true;
#pragma unroll
    for (int s = 0; s < SS; s++)
        fast = fast && (fabsf(expf(alog[i * SS + s]) - (float)(s + 1)) < 1e-3f);
    return fast;
}

// P/S layout (chunk-major): [c][b][i][s], offset = c*nbis + (b*II+i)*SS + s
// ---------------- scan pass A (packed-f32 core; last chunk skipped) ----------
__global__ __launch_bounds__(256) void k_scanA(const float* __restrict__ ssm,
                                               const unsigned short* __restrict__ u,
                                               const float* __restrict__ dtw,
                                               const float* __restrict__ dtb,
                                               const float* __restrict__ alog,
                                               float* __restrict__ P,
                                               float* __restrict__ S)
{
    __shared__ float sms[LCH][48];
    __shared__ unsigned short su[LCH][256];
    int tid = threadIdx.x;
    int i = blockIdx.x * 256 + tid;
    int c = blockIdx.y;                   // grid.y = NCCH-1 (last chunk dead)
    int b = blockIdx.z;
    int t0c = c * LCH;
    size_t nbis = (size_t)gridDim.z * II * SS;

    const float* srb = ssm + ((size_t)b * LSEQ + t0c) * 48;
    for (int v = tid; v < LCH * 12; v += 256) {
        int t = v / 12, q = v - t * 12;
        *(float4*)&sms[t][q * 4] = *(const float4*)(srb + (size_t)t * 48 + q * 4);
    }
    const unsigned short* ubase = u + ((size_t)b * LSEQ + t0c) * II + (blockIdx.x << 8);
    for (int v = tid; v < LCH * 32; v += 256) {
        int t = v >> 5, c8 = (v & 31) << 3;
        *(uint4*)&su[t][c8] = *(const uint4*)(ubase + (size_t)t * II + c8);
    }
    __syncthreads();

    float bias = dtb[i];
    size_t o = (size_t)c * nbis + (((size_t)b * II + i) * SS);

    if (a_is_integer(alog, i)) {
        f32x2 wdt2[8];
#pragma unroll
        for (int k = 0; k < 8; k++) wdt2[k] = *(const f32x2*)(dtw + i * RR + k * 2);
        f32x2 Sr2[8];
#pragma unroll
        for (int k = 0; k < 8; k++) Sr2[k] = (f32x2){0.f, 0.f};
        float dtsum = 0.f;
        for (int t = 0; t < LCH; t++) {
            const f32x2* a2 = (const f32x2*)&sms[t][0];
            f32x2 d2 = (f32x2){bias, 0.f};
#pragma unroll
            for (int k = 0; k < 8; k++) d2 = __builtin_elementwise_fma(a2[k], wdt2[k], d2);
            float dacc = d2.x + d2.y;
            float e   = __expf(-fabsf(dacc));
            float dtv = fmaxf(dacc, 0.f) + __logf(1.f + e);
            float r   = __expf(-dtv);
            dtsum += dtv;
            float uv = bf2f(su[t][tid]);
            float du = dtv * uv;
            f32x2 du2 = (f32x2){du, du};
            f32x2 pw2[8]; powtree2(r, pw2);
            const f32x2* bv2 = (const f32x2*)&sms[t][16];
#pragma unroll
            for (int k = 0; k < 8; k++)
                Sr2[k] = __builtin_elementwise_fma(pw2[k], Sr2[k], du2 * bv2[k]);
        }
        f32x2 Pr2[8]; powtree2(__expf(-dtsum), Pr2);
#pragma unroll
        for (int k = 0; k < 8; k++) {
            *(f32x2*)(P + o + k * 2) = Pr2[k];
            *(f32x2*)(S + o + k * 2) = Sr2[k];
        }
    } else {
        float wdt[16];
#pragma unroll
        for (int q = 0; q < 4; q++) *(float4*)&wdt[q*4] = *(const float4*)(dtw + i * RR + q * 4);
        float Ac[SS];
#pragma unroll
        for (int s = 0; s < SS; s++) Ac[s] = -expf(alog[i * SS + s]);
        float Sr[SS], Pr[SS];
#pragma unroll
        for (int s = 0; s < SS; s++) { Sr[s] = 0.f; Pr[s] = 1.f; }
        for (int t = 0; t < LCH; t++) {
            float dacc = bias;
#pragma unroll
            for (int q = 0; q < 4; q++) {
                float4 a = *(const float4*)&sms[t][q * 4];
                dacc = fmaf(a.x, wdt[q*4+0], dacc); dacc = fmaf(a.y, wdt[q*4+1], dacc);
                dacc = fmaf(a.z, wdt[q*4+2], dacc); dacc = fmaf(a.w, wdt[q*4+3], dacc);
            }
            float e   = __expf(-fabsf(dacc));
            float dtv = fmaxf(dacc, 0.f) + __logf(1.f + e);
            float uv = bf2f(su[t][tid]);
            float du = dtv * uv;
#pragma unroll
            for (int q = 0; q < 4; q++) {
                float4 bv = *(const float4*)&sms[t][16 + q * 4];
                float dA0 = __expf(dtv * Ac[q*4+0]), dA1 = __expf(dtv * Ac[q*4+1]);
                float dA2 = __expf(dtv * Ac[q*4+2]), dA3 = __expf(dtv * Ac[q*4+3]);
                Pr[q*4+0] *= dA0; Pr[q*4+1] *= dA1; Pr[q*4+2] *= dA2; Pr[q*4+3] *= dA3;
                Sr[q*4+0] = fmaf(dA0, Sr[q*4+0], du * bv.x);
                Sr[q*4+1] = fmaf(dA1, Sr[q*4+1], du * bv.y);
                Sr[q*4+2] = fmaf(dA2, Sr[q*4+2], du * bv.z);
                Sr[q*4+3] = fmaf(dA3, Sr[q*4+3], du * bv.w);
            }
        }
#pragma unroll
        for (int q = 0; q < 4; q++) {
            *(float4*)(P + o + q*4) = make_float4(Pr[q*4], Pr[q*4+1], Pr[q*4+2], Pr[q*4+3]);
            *(float4*)(S + o + q*4) = make_float4(Sr[q*4], Sr[q*4+1], Sr[q*4+2], Sr[q*4+3]);
        }
    }
}

// ---------------- scan pass B: per-(b,i,s) scalar carry, coalesced slices ------
__global__ __launch_bounds__(256) void k_scanB(float* __restrict__ P,
                                               const float* __restrict__ S,
                                               int nbis)
{
    int idx = blockIdx.x * 256 + threadIdx.x;
    float carry = 0.f;
#pragma unroll 4
    for (int c = 0; c < NCCH - 1; c++) {
        size_t o = (size_t)c * nbis + idx;
        float Pv = P[o];
        float Sv = S[o];
        float nc = fmaf(Pv, carry, Sv);
        P[o] = carry;
        carry = nc;
    }
    P[(size_t)(NCCH - 1) * nbis + idx] = carry;
}

// ---------------- scan pass C (packed-f32 core) + gate ----------------
__global__ __launch_bounds__(256) void k_scanC(const float* __restrict__ ssm,
                                               const unsigned short* __restrict__ u,
                                               const float* __restrict__ dtw,
                                               const float* __restrict__ dtb,
                                               const float* __restrict__ alog,
                                               const float* __restrict__ st0,
                                               unsigned short* proj,
                                               const float* __restrict__ Dp)
{
    __shared__ float sms[LCH][48];
    __shared__ unsigned short su[LCH][256];
    int tid = threadIdx.x;
    int i = blockIdx.x * 256 + tid;
    int c = blockIdx.y;
    int b = blockIdx.z;
    int t0c = c * LCH;
    size_t nbis = (size_t)gridDim.z * II * SS;

    const float* srb = ssm + ((size_t)b * LSEQ + t0c) * 48;
    for (int v = tid; v < LCH * 12; v += 256) {
        int t = v / 12, q = v - t * 12;
        *(float4*)&sms[t][q * 4] = *(const float4*)(srb + (size_t)t * 48 + q * 4);
    }
    const unsigned short* ubase = u + ((size_t)b * LSEQ + t0c) * II + (blockIdx.x << 8);
    for (int v = tid; v < LCH * 32; v += 256) {
        int t = v >> 5, c8 = (v & 31) << 3;
        *(uint4*)&su[t][c8] = *(const uint4*)(ubase + (size_t)t * II + c8);
    }
    __syncthreads();

    float bias = dtb[i];
    float Dv = Dp[i];
    size_t o = (size_t)c * nbis + (((size_t)b * II + i) * SS);

    const unsigned short* gp = proj + ((size_t)b * LSEQ + t0c) * 1024 + 512 + i;
    unsigned short*       yp = proj + ((size_t)b * LSEQ + t0c) * 1024 + i;

    if (a_is_integer(alog, i)) {
        f32x2 wdt2[8];
#pragma unroll
        for (int k = 0; k < 8; k++) wdt2[k] = *(const f32x2*)(dtw + i * RR + k * 2);
        f32x2 st2[8];
#pragma unroll
        for (int k = 0; k < 8; k++) st2[k] = *(const f32x2*)(st0 + o + k * 2);
        for (int t = 0; t < LCH; t++) {
            const f32x2* a2 = (const f32x2*)&sms[t][0];
            f32x2 d2 = (f32x2){bias, 0.f};
#pragma unroll
            for (int k = 0; k < 8; k++) d2 = __builtin_elementwise_fma(a2[k], wdt2[k], d2);
            float dacc = d2.x + d2.y;
            float e   = __expf(-fabsf(dacc));
            float dtv = fmaxf(dacc, 0.f) + __logf(1.f + e);
            float r   = __expf(-dtv);
            float uv = bf2f(su[t][tid]);
            float du = dtv * uv;
            f32x2 du2 = (f32x2){du, du};
            f32x2 pw2[8]; powtree2(r, pw2);
            const f32x2* bv2 = (const f32x2*)&sms[t][16];
            const f32x2* cv2 = (const f32x2*)&sms[t][32];
            f32x2 acc2 = (f32x2){0.f, 0.f};
#pragma unroll
            for (int k = 0; k < 8; k++) {
                st2[k] = __builtin_elementwise_fma(pw2[k], st2[k], du2 * bv2[k]);
                acc2 = __builtin_elementwise_fma(st2[k], cv2[k], acc2);
            }
            float acc = acc2.x + acc2.y;
            float yv = acc + uv * Dv;
            float gv = bf2f(gp[(size_t)t * 1024]);
            yp[(size_t)t * 1024] = f2bf(yv * silu_f(gv));
        }
    } else {
        float wdt[16];
#pragma unroll
        for (int q = 0; q < 4; q++) *(float4*)&wdt[q*4] = *(const float4*)(dtw + i * RR + q * 4);
        float Ac[SS];
#pragma unroll
        for (int s = 0; s < SS; s++) Ac[s] = -expf(alog[i * SS + s]);
        float st[SS];
#pragma unroll
        for (int q = 0; q < 4; q++) *(float4*)&st[q*4] = *(const float4*)(st0 + o + q*4);
        for (int t = 0; t < LCH; t++) {
            float dacc = bias;
#pragma unroll
            for (int q = 0; q < 4; q++) {
                float4 a = *(const float4*)&sms[t][q * 4];
                dacc = fmaf(a.x, wdt[q*4+0], dacc); dacc = fmaf(a.y, wdt[q*4+1], dacc);
                dacc = fmaf(a.z, wdt[q*4+2], dacc); dacc = fmaf(a.w, wdt[q*4+3], dacc);
            }
            float e   = __expf(-fabsf(dacc));
            float dtv = fmaxf(dacc, 0.f) + __logf(1.f + e);
            float uv = bf2f(su[t][tid]);
            float du = dtv * uv;
            float acc = 0.f;
#pragma unroll
            for (int q = 0; q < 4; q++) {
                float4 bv = *(const float4*)&sms[t][16 + q * 4];
                float4 cv = *(const float4*)&sms[t][32 + q * 4];
                float dA0 = __expf(dtv * Ac[q*4+0]), dA1 = __expf(dtv * Ac[q*4+1]);
                float dA2 = __expf(dtv * Ac[q*4+2]), dA3 = __expf(dtv * Ac[q*4+3]);
                st[q*4+0] = fmaf(dA0, st[q*4+0], du * bv.x);
                st[q*4+1] = fmaf(dA1, st[q*4+1], du * bv.y);
                st[q*4+2] = fmaf(dA2, st[q*4+2], du * bv.z);
                st[q*4+3] = fmaf(dA3, st[q*4+3], du * bv.w);
                acc = fmaf(st[q*4+0], cv.x, acc); acc = fmaf(st[q*4+1], cv.y, acc);
                acc = fmaf(st[q*4+2], cv.z, acc); acc = fmaf(st[q*4+3], cv.w, acc);
            }
            float yv = acc + uv * Dv;
            float gv = bf2f(gp[(size_t)t * 1024]);
            yp[(size_t)t * 1024] = f2bf(yv * silu_f(gv));
        }
    }
}

extern "C" void kernel_launch(void* const* d_in, const int* in_sizes, int n_in,
                              void* d_out, int out_size, void* d_ws, size_t ws_size,
                              hipStream_t stream)
{
    const float* x_in   = (const float*)d_in[0];
    const float* norm_w = (const float*)d_in[1];
    const float* in_w   = (const float*)d_in[2];
    const float* conv_w = (const float*)d_in[3];
    const float* conv_b = (const float*)d_in[4];
    const float* xp_w   = (const float*)d_in[5];
    const float* dt_w   = (const float*)d_in[6];
    const float* dt_b   = (const float*)d_in[7];
    const float* alog   = (const float*)d_in[8];
    const float* Dp     = (const float*)d_in[9];
    const float* out_w  = (const float*)d_in[10];
    float* out = (float*)d_out;   // persistent residual stream (fp32)

    const size_t w_in  = (size_t)NLAY * 2 * II * HID;
    const size_t w_out = (size_t)NLAY * HID * II;
    const size_t w_xp  = (size_t)NLAY * 48 * II;
    const size_t wbytes = (w_in + w_out + w_xp) * 2;

    // per-row floats: ssm 48 + P 256 + S 256 + h_bf 128 + proj_bf 512 + u_bf 256 = 1456
    int Bc = 1;
    for (int cand = BATCH; cand >= 1; cand >>= 1) {
        size_t need = (size_t)cand * LSEQ * 1456 * sizeof(float) + wbytes + (1 << 20);
        if (need <= ws_size) { Bc = cand; break; }
    }
    size_t Mc = (size_t)Bc * LSEQ;
    int ntm = (int)(Mc / 128);
    int nbis = Bc * II * SS;

    float* wsf = (float*)d_ws;
    float*          ssm     = wsf;
    float*          P       = wsf + Mc * 48;
    float*          S       = wsf + Mc * 304;
    unsigned short* h_bf    = (unsigned short*)(wsf + Mc * 560);
    unsigned short* proj_bf = (unsigned short*)(wsf + Mc * 688);   // [Mc,1024]
    unsigned short* u_bf    = (unsigned short*)(wsf + Mc * 1200);
    unsigned short* inw_bf  = (unsigned short*)(wsf + Mc * 1456);
    unsigned short* outw_bf = inw_bf + w_in;
    unsigned short* xpw_bf  = outw_bf + w_out;

    k_f2bf<<<2048, 256, 0, stream>>>(in_w,  inw_bf,  (int)w_in);
    k_f2bf<<<2048, 256, 0, stream>>>(out_w, outw_bf, (int)w_out);
    k_f2bf<<<2048, 256, 0, stream>>>(xp_w,  xpw_bf,  (int)w_xp);

    const int nchunk = BATCH / Bc;

    for (int l = 0; l < NLAY; l++) {
        for (int c = 0; c < nchunk; c++) {
            size_t row0 = (size_t)c * Mc;
            const float* xsrc = (l == 0) ? x_in + row0 * HID : out + row0 * HID;
            float*       dst  = out + row0 * HID;

            k_rmsnorm<<<(int)(Mc / 4), 256, 0, stream>>>(xsrc, norm_w + l * HID, h_bf);
            k_gemm_mfma<0,1><<<ntm * 8, 256, 0, stream>>>(
                h_bf, inw_bf + (size_t)l * 2 * II * HID, nullptr, proj_bf,
                2 * II, HID, HID, 8);
            k_conv_silu<<<dim3(LSEQ / 8, 2, Bc), 256, 0, stream>>>(
                proj_bf, conv_w + (size_t)l * II * KC, conv_b + (size_t)l * II, u_bf);
            k_gemm_mfma<0,0><<<ntm, 256, 0, stream>>>(
                u_bf, xpw_bf + (size_t)l * 48 * II, nullptr, ssm, 48, II, II, 1);
            k_scanA<<<dim3(II / 256, NCCH - 1, Bc), 256, 0, stream>>>(
                ssm, u_bf, dt_w + (size_t)l * II * RR, dt_b + (size_t)l * II,
                alog + (size_t)l * II * SS, P, S);
            k_scanB<<<nbis / 256, 256, 0, stream>>>(P, S, nbis);
            k_scanC<<<dim3(II / 256, NCCH, Bc), 256, 0, stream>>>(
                ssm, u_bf, dt_w + (size_t)l * II * RR, dt_b + (size_t)l * II,
                alog + (size_t)l * II * SS, P, proj_bf, Dp + (size_t)l * II);
            k_gemm_mfma<1,0><<<ntm * 2, 256, 0, stream>>>(
                proj_bf, outw_bf + (size_t)l * HID * II, xsrc, dst, HID, II, 2 * II, 2);
        }
    }
}

// Round 14
// 1979.736 us; speedup vs baseline: 1.0148x; 1.0148x over previous
//
#include <hip/hip_runtime.h>
#include <math.h>

#define HID 256
#define II 512
#define SS 16
#define RR 16
#define KC 4
#define NLAY 8
#define BATCH 16
#define LSEQ 2048
#define EPSV 1e-5f
#define NCCH 64
#define LCH (LSEQ/NCCH)   // 32
#define CSTR 130          // GEMM LDS epilogue row stride (ushorts)

typedef __attribute__((ext_vector_type(8))) short bf16x8;
typedef __attribute__((ext_vector_type(4))) float f32x4;
typedef __attribute__((ext_vector_type(2))) float f32x2;

#define GLOAD16(gp, lp) __builtin_amdgcn_global_load_lds( \
    (const __attribute__((address_space(1))) unsigned int*)(gp), \
    (__attribute__((address_space(3))) unsigned int*)(lp), 16, 0, 0)

__device__ __forceinline__ float silu_f(float x) { return x / (1.f + __expf(-x)); }
__device__ __forceinline__ float bf2f(unsigned short u) {
    union { unsigned int i; float f; } v; v.i = (unsigned int)u << 16; return v.f;
}
__device__ __forceinline__ unsigned short f2bf(float f) {
    union { float f; unsigned int i; } v; v.f = f;
    unsigned int r = v.i + 0x7FFFu + ((v.i >> 16) & 1u);
    return (unsigned short)(r >> 16);
}
// packed pow tree: pw[k] = {r^(2k+1), r^(2k+2)}
__device__ __forceinline__ void powtree2(float r, f32x2* pw) {
    float r2 = r * r;
    float r4 = r2 * r2;
    float r8 = r4 * r4;
    pw[0] = (f32x2){r, r2};
    pw[1] = pw[0] * r2;
    pw[2] = pw[0] * r4;
    pw[3] = pw[1] * r4;
    pw[4] = pw[0] * r8;
    pw[5] = pw[1] * r8;
    pw[6] = pw[2] * r8;
    pw[7] = pw[3] * r8;
}

// ---------------- f32 -> bf16 weight conversion ----------------
__global__ __launch_bounds__(256) void k_f2bf(const float* __restrict__ in,
                                              unsigned short* __restrict__ out, int n)
{
    for (int i = blockIdx.x * 256 + threadIdx.x; i < n; i += gridDim.x * 256)
        out[i] = f2bf(in[i]);
}

// ---------------- RMSNorm -> bf16 ----------------
__global__ __launch_bounds__(256) void k_rmsnorm(const float* __restrict__ x,
                                                 const float* __restrict__ w,
                                                 unsigned short* __restrict__ out)
{
    int wave = threadIdx.x >> 6;
    int lane = threadIdx.x & 63;
    int row  = blockIdx.x * 4 + wave;
    const float* xr = x + (size_t)row * HID;
    float4 v = *(const float4*)(xr + lane * 4);
    float ss = v.x*v.x + v.y*v.y + v.z*v.z + v.w*v.w;
#pragma unroll
    for (int off = 32; off >= 1; off >>= 1) ss += __shfl_xor(ss, off, 64);
    float inv = 1.0f / sqrtf(ss * (1.0f / (float)HID) + EPSV);
    float4 wv = *(const float4*)(w + lane * 4);
    ushort4 o;
    o.x = f2bf(v.x * inv * wv.x); o.y = f2bf(v.y * inv * wv.y);
    o.z = f2bf(v.z * inv * wv.z); o.w = f2bf(v.w * inv * wv.w);
    *(ushort4*)(out + (size_t)row * HID + lane * 4) = o;
}

// ---------------- bf16 MFMA GEMM (m97 structure) ----------------
template<int RESID, int OUTBF>
__global__ __launch_bounds__(256) void k_gemm_mfma(const unsigned short* __restrict__ A,
                                                   const unsigned short* __restrict__ Bw,
                                                   const float* __restrict__ resid,
                                                   void* __restrict__ Cout,
                                                   int N, int K, int lda, int ntn)
{
    __shared__ unsigned short smem[16640];
    unsigned short* As = smem;
    unsigned short* Bs = smem + 8192;

    int ntm = gridDim.x / ntn;
    int mpx = ntm >> 3;
    int bid = blockIdx.x;
    int xcd = bid & 7, jj0 = bid >> 3;
    int mt = xcd * mpx + (jj0 % mpx);
    int nt = jj0 / mpx;
    int bm = mt * 128, bn = nt * 128;

    int tid = threadIdx.x;
    int wave = tid >> 6, lane = tid & 63;
    int wr = wave >> 1, wc = wave & 1;

    f32x4 acc[4][4];
#pragma unroll
    for (int mi = 0; mi < 4; mi++)
#pragma unroll
        for (int ni = 0; ni < 4; ni++) acc[mi][ni] = (f32x4){0.f, 0.f, 0.f, 0.f};

    int grp0 = wave * 4;
    int rr = lane >> 3, sl = lane & 7;
    int r = lane & 15, ks = lane >> 4;

    for (int k0 = 0; k0 < K; k0 += 64) {
        __syncthreads();
#pragma unroll
        for (int j = 0; j < 4; j++) {
            int g = grp0 + j;
            int row = g * 8 + rr;
            int ss = sl ^ (row & 7);
            GLOAD16(A + (size_t)(bm + row) * lda + k0 + ss * 8, As + g * 512);
            int br = bn + row; if (br > N - 1) br = N - 1;
            GLOAD16(Bw + (size_t)br * K + k0 + ss * 8, Bs + g * 512);
        }
        __syncthreads();
#pragma unroll
        for (int kk = 0; kk < 2; kk++) {
            bf16x8 af[4], bfv[4];
#pragma unroll
            for (int mi = 0; mi < 4; mi++) {
                int row = wr * 64 + mi * 16 + r;
                int boff = row * 128 + (((kk * 4 + ks) ^ (row & 7)) << 4);
                af[mi] = *(const bf16x8*)((const char*)As + boff);
            }
#pragma unroll
            for (int ni = 0; ni < 4; ni++) {
                int row = wc * 64 + ni * 16 + r;
                int boff = row * 128 + (((kk * 4 + ks) ^ (row & 7)) << 4);
                bfv[ni] = *(const bf16x8*)((const char*)Bs + boff);
            }
#pragma unroll
            for (int mi = 0; mi < 4; mi++)
#pragma unroll
                for (int ni = 0; ni < 4; ni++)
                    acc[mi][ni] = __builtin_amdgcn_mfma_f32_16x16x32_bf16(
                        af[mi], bfv[ni], acc[mi][ni], 0, 0, 0);
        }
    }

    int ccol = lane & 15, crow0 = (lane >> 4) * 4;
    if (OUTBF) {
        __syncthreads();
        unsigned short* Cs = smem;
#pragma unroll
        for (int mi = 0; mi < 4; mi++)
#pragma unroll
            for (int ni = 0; ni < 4; ni++) {
                int row = wr * 64 + mi * 16 + crow0;
                int col = wc * 64 + ni * 16 + ccol;
#pragma unroll
                for (int j = 0; j < 4; j++)
                    Cs[(row + j) * CSTR + col] = f2bf(acc[mi][ni][j]);
            }
        __syncthreads();
#pragma unroll
        for (int it = 0; it < 8; it++) {
            int idx = it * 256 + tid;
            int row = idx >> 4, ch = idx & 15;
            uint4 v = *(const uint4*)(Cs + row * CSTR + ch * 8);
            *(uint4*)((unsigned short*)Cout + (size_t)(bm + row) * N + bn + ch * 8) = v;
        }
    } else {
#pragma unroll
        for (int mi = 0; mi < 4; mi++)
#pragma unroll
            for (int ni = 0; ni < 4; ni++) {
                int gc = bn + wc * 64 + ni * 16 + ccol;
                if (gc < N) {
#pragma unroll
                    for (int j = 0; j < 4; j++) {
                        int gr = bm + wr * 64 + mi * 16 + crow0 + j;
                        float v = acc[mi][ni][j];
                        size_t off = (size_t)gr * N + gc;
                        if (RESID) v += resid[off];
                        ((float*)Cout)[off] = v;
                    }
                }
            }
    }
}

// ---------------- depthwise causal conv (K=4) + bias + SiLU ----------------
__global__ __launch_bounds__(256) void k_conv_silu(const unsigned short* __restrict__ proj,
                                                   const float* __restrict__ cw,
                                                   const float* __restrict__ cb,
                                                   unsigned short* __restrict__ u)
{
    __shared__ float sm[11][256];
    int tx = threadIdx.x;
    int t0 = blockIdx.x * 8;
    int i  = blockIdx.y * 256 + tx;
    int b  = blockIdx.z;
#pragma unroll
    for (int r = 0; r < 11; r++) {
        int t = t0 - 3 + r;
        float val = 0.f;
        if (t >= 0) val = bf2f(proj[(size_t)(b * LSEQ + t) * 1024 + i]);
        sm[r][tx] = val;
    }
    __syncthreads();
    float w0 = cw[i * KC + 0], w1 = cw[i * KC + 1], w2 = cw[i * KC + 2], w3 = cw[i * KC + 3];
    float bias = cb[i];
#pragma unroll
    for (int r = 0; r < 8; r++) {
        float s = sm[r][tx] * w0 + sm[r+1][tx] * w1 + sm[r+2][tx] * w2 + sm[r+3][tx] * w3 + bias;
        u[(size_t)(b * LSEQ + t0 + r) * II + i] = f2bf(silu_f(s));
    }
}

// detect A[i,s] == -(s+1) (reference init) -> pow-chain fast path
__device__ __forceinline__ bool a_is_integer(const float* alog, int i) {
    bool fast = true;
#pragma unroll
    for (int s = 0; s < SS; s++)
        fast = fast && (fabsf(expf(alog[i * SS + s]) - (float)(s + 1)) < 1e-3f);
    return fast;
}

// ---------------- slow-path helpers (general A) ----------------
__device__ void scanA_slow_one(const float (*sm)[48], const unsigned short* up,
                               const float* wdt, const float* Ac, float bias,
                               float* Pr, float* Sr)
{
#pragma unroll
    for (int s = 0; s < SS; s++) { Pr[s] = 1.f; Sr[s] = 0.f; }
    for (int t = 0; t < LCH; t++) {
        float dacc = bias;
#pragma unroll
        for (int q = 0; q < 4; q++) {
            float4 a = *(const float4*)&sm[t][q * 4];
            dacc = fmaf(a.x, wdt[q*4+0], dacc); dacc = fmaf(a.y, wdt[q*4+1], dacc);
            dacc = fmaf(a.z, wdt[q*4+2], dacc); dacc = fmaf(a.w, wdt[q*4+3], dacc);
        }
        float e   = __expf(-fabsf(dacc));
        float dtv = fmaxf(dacc, 0.f) + __logf(1.f + e);
        float uv = bf2f(up[(size_t)t * II]);
        float du = dtv * uv;
#pragma unroll
        for (int q = 0; q < 4; q++) {
            float4 bv = *(const float4*)&sm[t][16 + q * 4];
            float dA0 = __expf(dtv * Ac[q*4+0]), dA1 = __expf(dtv * Ac[q*4+1]);
            float dA2 = __expf(dtv * Ac[q*4+2]), dA3 = __expf(dtv * Ac[q*4+3]);
            Pr[q*4+0] *= dA0; Pr[q*4+1] *= dA1; Pr[q*4+2] *= dA2; Pr[q*4+3] *= dA3;
            Sr[q*4+0] = fmaf(dA0, Sr[q*4+0], du * bv.x);
            Sr[q*4+1] = fmaf(dA1, Sr[q*4+1], du * bv.y);
            Sr[q*4+2] = fmaf(dA2, Sr[q*4+2], du * bv.z);
            Sr[q*4+3] = fmaf(dA3, Sr[q*4+3], du * bv.w);
        }
    }
}

__device__ void scanC_slow_one(const float (*sm)[48], const unsigned short* up,
                               const unsigned short* gp, unsigned short* yp,
                               const float* wdt, const float* Ac, float bias,
                               float Dv, float* st)
{
    for (int t = 0; t < LCH; t++) {
        float dacc = bias;
#pragma unroll
        for (int q = 0; q < 4; q++) {
            float4 a = *(const float4*)&sm[t][q * 4];
            dacc = fmaf(a.x, wdt[q*4+0], dacc); dacc = fmaf(a.y, wdt[q*4+1], dacc);
            dacc = fmaf(a.z, wdt[q*4+2], dacc); dacc = fmaf(a.w, wdt[q*4+3], dacc);
        }
        float e   = __expf(-fabsf(dacc));
        float dtv = fmaxf(dacc, 0.f) + __logf(1.f + e);
        float uv = bf2f(up[(size_t)t * II]);
        float du = dtv * uv;
        float acc = 0.f;
#pragma unroll
        for (int q = 0; q < 4; q++) {
            float4 bv = *(const float4*)&sm[t][16 + q * 4];
            float4 cv = *(const float4*)&sm[t][32 + q * 4];
            float dA0 = __expf(dtv * Ac[q*4+0]), dA1 = __expf(dtv * Ac[q*4+1]);
            float dA2 = __expf(dtv * Ac[q*4+2]), dA3 = __expf(dtv * Ac[q*4+3]);
            st[q*4+0] = fmaf(dA0, st[q*4+0], du * bv.x);
            st[q*4+1] = fmaf(dA1, st[q*4+1], du * bv.y);
            st[q*4+2] = fmaf(dA2, st[q*4+2], du * bv.z);
            st[q*4+3] = fmaf(dA3, st[q*4+3], du * bv.w);
            acc = fmaf(st[q*4+0], cv.x, acc); acc = fmaf(st[q*4+1], cv.y, acc);
            acc = fmaf(st[q*4+2], cv.z, acc); acc = fmaf(st[q*4+3], cv.w, acc);
        }
        float yv = acc + uv * Dv;
        float gv = bf2f(gp[(size_t)t * 1024]);
        yp[(size_t)t * 1024] = f2bf(yv * silu_f(gv));
    }
}

// P/S layout (chunk-major): [c][b][i][s], offset = c*nbis + (b*II+i)*SS + s
// ---------------- scan pass A: 2 chunk-chains per thread (c, c+32) -------------
__global__ __launch_bounds__(256) void k_scanA(const float* __restrict__ ssm,
                                               const unsigned short* __restrict__ u,
                                               const float* __restrict__ dtw,
                                               const float* __restrict__ dtb,
                                               const float* __restrict__ alog,
                                               float* __restrict__ P,
                                               float* __restrict__ S)
{
    __shared__ float sms[2][LCH][48];
    int tid = threadIdx.x;
    int i = blockIdx.x * 256 + tid;
    int c = blockIdx.y;                    // 0..31; chain B = c+32
    int b = blockIdx.z;
    int cB = c + 32;
    bool twoOut = (cB < NCCH - 1);         // chunk 63 output dead
    size_t nbis = (size_t)gridDim.z * II * SS;

    const float* srbA = ssm + ((size_t)b * LSEQ + c * LCH) * 48;
    const float* srbB = ssm + ((size_t)b * LSEQ + cB * LCH) * 48;
    for (int v = tid; v < LCH * 12; v += 256) {
        int t = v / 12, q = v - t * 12;
        *(float4*)&sms[0][t][q * 4] = *(const float4*)(srbA + (size_t)t * 48 + q * 4);
        *(float4*)&sms[1][t][q * 4] = *(const float4*)(srbB + (size_t)t * 48 + q * 4);
    }
    __syncthreads();

    float bias = dtb[i];
    const unsigned short* upA = u + ((size_t)b * LSEQ + c * LCH) * II + i;
    const unsigned short* upB = u + ((size_t)b * LSEQ + cB * LCH) * II + i;
    size_t oA = (size_t)c * nbis + (((size_t)b * II + i) * SS);
    size_t oB = (size_t)cB * nbis + (((size_t)b * II + i) * SS);

    if (a_is_integer(alog, i)) {
        f32x2 wdt2[8];
#pragma unroll
        for (int k = 0; k < 8; k++) wdt2[k] = *(const f32x2*)(dtw + i * RR + k * 2);
        f32x2 SrA[8], SrB[8];
#pragma unroll
        for (int k = 0; k < 8; k++) { SrA[k] = (f32x2){0.f, 0.f}; SrB[k] = (f32x2){0.f, 0.f}; }
        float dtsumA = 0.f, dtsumB = 0.f;
        for (int t = 0; t < LCH; t++) {
            const f32x2* aA = (const f32x2*)&sms[0][t][0];
            const f32x2* aB = (const f32x2*)&sms[1][t][0];
            f32x2 dA2 = (f32x2){bias, 0.f}, dB2 = (f32x2){bias, 0.f};
#pragma unroll
            for (int k = 0; k < 8; k++) {
                dA2 = __builtin_elementwise_fma(aA[k], wdt2[k], dA2);
                dB2 = __builtin_elementwise_fma(aB[k], wdt2[k], dB2);
            }
            float daccA = dA2.x + dA2.y, daccB = dB2.x + dB2.y;
            float eA = __expf(-fabsf(daccA)), eB = __expf(-fabsf(daccB));
            float dtA = fmaxf(daccA, 0.f) + __logf(1.f + eA);
            float dtB = fmaxf(daccB, 0.f) + __logf(1.f + eB);
            float rA = __expf(-dtA), rB = __expf(-dtB);
            dtsumA += dtA; dtsumB += dtB;
            float uvA = bf2f(upA[(size_t)t * II]), uvB = bf2f(upB[(size_t)t * II]);
            float duA = dtA * uvA, duB = dtB * uvB;
            f32x2 duA2 = (f32x2){duA, duA}, duB2 = (f32x2){duB, duB};
            f32x2 pwA[8], pwB[8];
            powtree2(rA, pwA); powtree2(rB, pwB);
            const f32x2* bvA = (const f32x2*)&sms[0][t][16];
            const f32x2* bvB = (const f32x2*)&sms[1][t][16];
#pragma unroll
            for (int k = 0; k < 8; k++) {
                SrA[k] = __builtin_elementwise_fma(pwA[k], SrA[k], duA2 * bvA[k]);
                SrB[k] = __builtin_elementwise_fma(pwB[k], SrB[k], duB2 * bvB[k]);
            }
        }
        f32x2 PrA[8]; powtree2(__expf(-dtsumA), PrA);
#pragma unroll
        for (int k = 0; k < 8; k++) {
            *(f32x2*)(P + oA + k * 2) = PrA[k];
            *(f32x2*)(S + oA + k * 2) = SrA[k];
        }
        if (twoOut) {
            f32x2 PrB[8]; powtree2(__expf(-dtsumB), PrB);
#pragma unroll
            for (int k = 0; k < 8; k++) {
                *(f32x2*)(P + oB + k * 2) = PrB[k];
                *(f32x2*)(S + oB + k * 2) = SrB[k];
            }
        }
    } else {
        float wdt[16];
#pragma unroll
        for (int q = 0; q < 4; q++) *(float4*)&wdt[q*4] = *(const float4*)(dtw + i * RR + q * 4);
        float Ac[SS];
#pragma unroll
        for (int s = 0; s < SS; s++) Ac[s] = -expf(alog[i * SS + s]);
        float Pr[SS], Sr[SS];
        scanA_slow_one(sms[0], upA, wdt, Ac, bias, Pr, Sr);
#pragma unroll
        for (int q = 0; q < 4; q++) {
            *(float4*)(P + oA + q*4) = make_float4(Pr[q*4], Pr[q*4+1], Pr[q*4+2], Pr[q*4+3]);
            *(float4*)(S + oA + q*4) = make_float4(Sr[q*4], Sr[q*4+1], Sr[q*4+2], Sr[q*4+3]);
        }
        if (twoOut) {
            scanA_slow_one(sms[1], upB, wdt, Ac, bias, Pr, Sr);
#pragma unroll
            for (int q = 0; q < 4; q++) {
                *(float4*)(P + oB + q*4) = make_float4(Pr[q*4], Pr[q*4+1], Pr[q*4+2], Pr[q*4+3]);
                *(float4*)(S + oB + q*4) = make_float4(Sr[q*4], Sr[q*4+1], Sr[q*4+2], Sr[q*4+3]);
            }
        }
    }
}

// ---------------- scan pass B: per-(b,i,s) scalar carry, coalesced slices ------
__global__ __launch_bounds__(256) void k_scanB(float* __restrict__ P,
                                               const float* __restrict__ S,
                                               int nbis)
{
    int idx = blockIdx.x * 256 + threadIdx.x;
    float carry = 0.f;
#pragma unroll 4
    for (int c = 0; c < NCCH - 1; c++) {
        size_t o = (size_t)c * nbis + idx;
        float Pv = P[o];
        float Sv = S[o];
        float nc = fmaf(Pv, carry, Sv);
        P[o] = carry;
        carry = nc;
    }
    P[(size_t)(NCCH - 1) * nbis + idx] = carry;
}

// ---------------- scan pass C: 2 chunk-chains per thread (c, c+32) + gate ------
__global__ __launch_bounds__(256) void k_scanC(const float* __restrict__ ssm,
                                               const unsigned short* __restrict__ u,
                                               const float* __restrict__ dtw,
                                               const float* __restrict__ dtb,
                                               const float* __restrict__ alog,
                                               const float* __restrict__ st0,
                                               unsigned short* proj,
                                               const float* __restrict__ Dp)
{
    __shared__ float sms[2][LCH][48];
    int tid = threadIdx.x;
    int i = blockIdx.x * 256 + tid;
    int c = blockIdx.y;                    // 0..31; chain B = c+32
    int b = blockIdx.z;
    int cB = c + 32;
    size_t nbis = (size_t)gridDim.z * II * SS;

    const float* srbA = ssm + ((size_t)b * LSEQ + c * LCH) * 48;
    const float* srbB = ssm + ((size_t)b * LSEQ + cB * LCH) * 48;
    for (int v = tid; v < LCH * 12; v += 256) {
        int t = v / 12, q = v - t * 12;
        *(float4*)&sms[0][t][q * 4] = *(const float4*)(srbA + (size_t)t * 48 + q * 4);
        *(float4*)&sms[1][t][q * 4] = *(const float4*)(srbB + (size_t)t * 48 + q * 4);
    }
    __syncthreads();

    float bias = dtb[i];
    float Dv = Dp[i];
    size_t oA = (size_t)c * nbis + (((size_t)b * II + i) * SS);
    size_t oB = (size_t)cB * nbis + (((size_t)b * II + i) * SS);

    const unsigned short* upA = u + ((size_t)b * LSEQ + c * LCH) * II + i;
    const unsigned short* upB = u + ((size_t)b * LSEQ + cB * LCH) * II + i;
    const unsigned short* gpA = proj + ((size_t)b * LSEQ + c * LCH) * 1024 + 512 + i;
    const unsigned short* gpB = proj + ((size_t)b * LSEQ + cB * LCH) * 1024 + 512 + i;
    unsigned short* ypA = proj + ((size_t)b * LSEQ + c * LCH) * 1024 + i;
    unsigned short* ypB = proj + ((size_t)b * LSEQ + cB * LCH) * 1024 + i;

    if (a_is_integer(alog, i)) {
        f32x2 wdt2[8];
#pragma unroll
        for (int k = 0; k < 8; k++) wdt2[k] = *(const f32x2*)(dtw + i * RR + k * 2);
        f32x2 stA[8], stB[8];
#pragma unroll
        for (int k = 0; k < 8; k++) {
            stA[k] = *(const f32x2*)(st0 + oA + k * 2);
            stB[k] = *(const f32x2*)(st0 + oB + k * 2);
        }
        for (int t = 0; t < LCH; t++) {
            const f32x2* aA = (const f32x2*)&sms[0][t][0];
            const f32x2* aB = (const f32x2*)&sms[1][t][0];
            f32x2 dA2 = (f32x2){bias, 0.f}, dB2 = (f32x2){bias, 0.f};
#pragma unroll
            for (int k = 0; k < 8; k++) {
                dA2 = __builtin_elementwise_fma(aA[k], wdt2[k], dA2);
                dB2 = __builtin_elementwise_fma(aB[k], wdt2[k], dB2);
            }
            float daccA = dA2.x + dA2.y, daccB = dB2.x + dB2.y;
            float eA = __expf(-fabsf(daccA)), eB = __expf(-fabsf(daccB));
            float dtA = fmaxf(daccA, 0.f) + __logf(1.f + eA);
            float dtB = fmaxf(daccB, 0.f) + __logf(1.f + eB);
            float rA = __expf(-dtA), rB = __expf(-dtB);
            float uvA = bf2f(upA[(size_t)t * II]), uvB = bf2f(upB[(size_t)t * II]);
            float duA = dtA * uvA, duB = dtB * uvB;
            f32x2 duA2 = (f32x2){duA, duA}, duB2 = (f32x2){duB, duB};
            f32x2 pwA[8], pwB[8];
            powtree2(rA, pwA); powtree2(rB, pwB);
            const f32x2* bvA = (const f32x2*)&sms[0][t][16];
            const f32x2* bvB = (const f32x2*)&sms[1][t][16];
            const f32x2* cvA = (const f32x2*)&sms[0][t][32];
            const f32x2* cvB = (const f32x2*)&sms[1][t][32];
            f32x2 accA = (f32x2){0.f, 0.f}, accB = (f32x2){0.f, 0.f};
#pragma unroll
            for (int k = 0; k < 8; k++) {
                stA[k] = __builtin_elementwise_fma(pwA[k], stA[k], duA2 * bvA[k]);
                stB[k] = __builtin_elementwise_fma(pwB[k], stB[k], duB2 * bvB[k]);
                accA = __builtin_elementwise_fma(stA[k], cvA[k], accA);
                accB = __builtin_elementwise_fma(stB[k], cvB[k], accB);
            }
            float yvA = (accA.x + accA.y) + uvA * Dv;
            float yvB = (accB.x + accB.y) + uvB * Dv;
            float gvA = bf2f(gpA[(size_t)t * 1024]);
            float gvB = bf2f(gpB[(size_t)t * 1024]);
            ypA[(size_t)t * 1024] = f2bf(yvA * silu_f(gvA));
            ypB[(size_t)t * 1024] = f2bf(yvB * silu_f(gvB));
        }
    } else {
        float wdt[16];
#pragma unroll
        for (int q = 0; q < 4; q++) *(float4*)&wdt[q*4] = *(const float4*)(dtw + i * RR + q * 4);
        float Ac[SS];
#pragma unroll
        for (int s = 0; s < SS; s++) Ac[s] = -expf(alog[i * SS + s]);
        float st[SS];
#pragma unroll
        for (int q = 0; q < 4; q++) *(float4*)&st[q*4] = *(const float4*)(st0 + oA + q*4);
        scanC_slow_one(sms[0], upA, gpA, ypA, wdt, Ac, bias, Dv, st);
#pragma unroll
        for (int q = 0; q < 4; q++) *(float4*)&st[q*4] = *(const float4*)(st0 + oB + q*4);
        scanC_slow_one(sms[1], upB, gpB, ypB, wdt, Ac, bias, Dv, st);
    }
}

extern "C" void kernel_launch(void* const* d_in, const int* in_sizes, int n_in,
                              void* d_out, int out_size, void* d_ws, size_t ws_size,
                              hipStream_t stream)
{
    const float* x_in   = (const float*)d_in[0];
    const float* norm_w = (const float*)d_in[1];
    const float* in_w   = (const float*)d_in[2];
    const float* conv_w = (const float*)d_in[3];
    const float* conv_b = (const float*)d_in[4];
    const float* xp_w   = (const float*)d_in[5];
    const float* dt_w   = (const float*)d_in[6];
    const float* dt_b   = (const float*)d_in[7];
    const float* alog   = (const float*)d_in[8];
    const float* Dp     = (const float*)d_in[9];
    const float* out_w  = (const float*)d_in[10];
    float* out = (float*)d_out;   // persistent residual stream (fp32)

    const size_t w_in  = (size_t)NLAY * 2 * II * HID;
    const size_t w_out = (size_t)NLAY * HID * II;
    const size_t w_xp  = (size_t)NLAY * 48 * II;
    const size_t wbytes = (w_in + w_out + w_xp) * 2;

    // per-row floats: ssm 48 + P 256 + S 256 + h_bf 128 + proj_bf 512 + u_bf 256 = 1456
    int Bc = 1;
    for (int cand = BATCH; cand >= 1; cand >>= 1) {
        size_t need = (size_t)cand * LSEQ * 1456 * sizeof(float) + wbytes + (1 << 20);
        if (need <= ws_size) { Bc = cand; break; }
    }
    size_t Mc = (size_t)Bc * LSEQ;
    int ntm = (int)(Mc / 128);
    int nbis = Bc * II * SS;

    float* wsf = (float*)d_ws;
    float*          ssm     = wsf;
    float*          P       = wsf + Mc * 48;
    float*          S       = wsf + Mc * 304;
    unsigned short* h_bf    = (unsigned short*)(wsf + Mc * 560);
    unsigned short* proj_bf = (unsigned short*)(wsf + Mc * 688);   // [Mc,1024]
    unsigned short* u_bf    = (unsigned short*)(wsf + Mc * 1200);
    unsigned short* inw_bf  = (unsigned short*)(wsf + Mc * 1456);
    unsigned short* outw_bf = inw_bf + w_in;
    unsigned short* xpw_bf  = outw_bf + w_out;

    k_f2bf<<<2048, 256, 0, stream>>>(in_w,  inw_bf,  (int)w_in);
    k_f2bf<<<2048, 256, 0, stream>>>(out_w, outw_bf, (int)w_out);
    k_f2bf<<<2048, 256, 0, stream>>>(xp_w,  xpw_bf,  (int)w_xp);

    const int nchunk = BATCH / Bc;

    for (int l = 0; l < NLAY; l++) {
        for (int c = 0; c < nchunk; c++) {
            size_t row0 = (size_t)c * Mc;
            const float* xsrc = (l == 0) ? x_in + row0 * HID : out + row0 * HID;
            float*       dst  = out + row0 * HID;

            k_rmsnorm<<<(int)(Mc / 4), 256, 0, stream>>>(xsrc, norm_w + l * HID, h_bf);
            k_gemm_mfma<0,1><<<ntm * 8, 256, 0, stream>>>(
                h_bf, inw_bf + (size_t)l * 2 * II * HID, nullptr, proj_bf,
                2 * II, HID, HID, 8);
            k_conv_silu<<<dim3(LSEQ / 8, 2, Bc), 256, 0, stream>>>(
                proj_bf, conv_w + (size_t)l * II * KC, conv_b + (size_t)l * II, u_bf);
            k_gemm_mfma<0,0><<<ntm, 256, 0, stream>>>(
                u_bf, xpw_bf + (size_t)l * 48 * II, nullptr, ssm, 48, II, II, 1);
            k_scanA<<<dim3(II / 256, NCCH / 2, Bc), 256, 0, stream>>>(
                ssm, u_bf, dt_w + (size_t)l * II * RR, dt_b + (size_t)l * II,
                alog + (size_t)l * II * SS, P, S);
            k_scanB<<<nbis / 256, 256, 0, stream>>>(P, S, nbis);
            k_scanC<<<dim3(II / 256, NCCH / 2, Bc), 256, 0, stream>>>(
                ssm, u_bf, dt_w + (size_t)l * II * RR, dt_b + (size_t)l * II,
                alog + (size_t)l * II * SS, P, proj_bf, Dp + (size_t)l * II);
            k_gemm_mfma<1,0><<<ntm * 2, 256, 0, stream>>>(
                proj_bf, outw_bf + (size_t)l * HID * II, xsrc, dst, HID, II, 2 * II, 2);
        }
    }
}

// Round 16
// 1919.582 us; speedup vs baseline: 1.0466x; 1.0313x over previous
//
#include <hip/hip_runtime.h>
#include <math.h>

#define HID 256
#define II 512
#define SS 16
#define RR 16
#define KC 4
#define NLAY 8
#define BATCH 16
#define LSEQ 2048
#define EPSV 1e-5f
#define NCCH 64
#define LCH (LSEQ/NCCH)   // 32
#define CSTR 130          // GEMM LDS epilogue row stride (ushorts)

typedef __attribute__((ext_vector_type(8))) short bf16x8;
typedef __attribute__((ext_vector_type(4))) float f32x4;
typedef __attribute__((ext_vector_type(2))) float f32x2;

#define GLOAD16(gp, lp) __builtin_amdgcn_global_load_lds( \
    (const __attribute__((address_space(1))) unsigned int*)(gp), \
    (__attribute__((address_space(3))) unsigned int*)(lp), 16, 0, 0)

__device__ __forceinline__ float silu_f(float x) { return x / (1.f + __expf(-x)); }
__device__ __forceinline__ float bf2f(unsigned short u) {
    union { unsigned int i; float f; } v; v.i = (unsigned int)u << 16; return v.f;
}
__device__ __forceinline__ unsigned short f2bf(float f) {
    union { float f; unsigned int i; } v; v.f = f;
    unsigned int r = v.i + 0x7FFFu + ((v.i >> 16) & 1u);
    return (unsigned short)(r >> 16);
}
// packed pow tree: pw[k] = {r^(2k+1), r^(2k+2)}
__device__ __forceinline__ void powtree2(float r, f32x2* pw) {
    float r2 = r * r;
    float r4 = r2 * r2;
    float r8 = r4 * r4;
    pw[0] = (f32x2){r, r2};
    pw[1] = pw[0] * r2;
    pw[2] = pw[0] * r4;
    pw[3] = pw[1] * r4;
    pw[4] = pw[0] * r8;
    pw[5] = pw[1] * r8;
    pw[6] = pw[2] * r8;
    pw[7] = pw[3] * r8;
}

// ---------------- f32 -> bf16 weight conversion ----------------
__global__ __launch_bounds__(256) void k_f2bf(const float* __restrict__ in,
                                              unsigned short* __restrict__ out, int n)
{
    for (int i = blockIdx.x * 256 + threadIdx.x; i < n; i += gridDim.x * 256)
        out[i] = f2bf(in[i]);
}

// ---------------- RMSNorm -> bf16 ----------------
__global__ __launch_bounds__(256) void k_rmsnorm(const float* __restrict__ x,
                                                 const float* __restrict__ w,
                                                 unsigned short* __restrict__ out)
{
    int wave = threadIdx.x >> 6;
    int lane = threadIdx.x & 63;
    int row  = blockIdx.x * 4 + wave;
    const float* xr = x + (size_t)row * HID;
    float4 v = *(const float4*)(xr + lane * 4);
    float ss = v.x*v.x + v.y*v.y + v.z*v.z + v.w*v.w;
#pragma unroll
    for (int off = 32; off >= 1; off >>= 1) ss += __shfl_xor(ss, off, 64);
    float inv = 1.0f / sqrtf(ss * (1.0f / (float)HID) + EPSV);
    float4 wv = *(const float4*)(w + lane * 4);
    ushort4 o;
    o.x = f2bf(v.x * inv * wv.x); o.y = f2bf(v.y * inv * wv.y);
    o.z = f2bf(v.z * inv * wv.z); o.w = f2bf(v.w * inv * wv.w);
    *(ushort4*)(out + (size_t)row * HID + lane * 4) = o;
}

// ---------------- bf16 MFMA GEMM (m97 structure) ----------------
template<int RESID, int OUTBF>
__global__ __launch_bounds__(256) void k_gemm_mfma(const unsigned short* __restrict__ A,
                                                   const unsigned short* __restrict__ Bw,
                                                   const float* __restrict__ resid,
                                                   void* __restrict__ Cout,
                                                   int N, int K, int lda, int ntn)
{
    __shared__ unsigned short smem[16640];
    unsigned short* As = smem;
    unsigned short* Bs = smem + 8192;

    int ntm = gridDim.x / ntn;
    int mpx = ntm >> 3;
    int bid = blockIdx.x;
    int xcd = bid & 7, jj0 = bid >> 3;
    int mt = xcd * mpx + (jj0 % mpx);
    int nt = jj0 / mpx;
    int bm = mt * 128, bn = nt * 128;

    int tid = threadIdx.x;
    int wave = tid >> 6, lane = tid & 63;
    int wr = wave >> 1, wc = wave & 1;

    f32x4 acc[4][4];
#pragma unroll
    for (int mi = 0; mi < 4; mi++)
#pragma unroll
        for (int ni = 0; ni < 4; ni++) acc[mi][ni] = (f32x4){0.f, 0.f, 0.f, 0.f};

    int grp0 = wave * 4;
    int rr = lane >> 3, sl = lane & 7;
    int r = lane & 15, ks = lane >> 4;

    for (int k0 = 0; k0 < K; k0 += 64) {
        __syncthreads();
#pragma unroll
        for (int j = 0; j < 4; j++) {
            int g = grp0 + j;
            int row = g * 8 + rr;
            int ss = sl ^ (row & 7);
            GLOAD16(A + (size_t)(bm + row) * lda + k0 + ss * 8, As + g * 512);
            int br = bn + row; if (br > N - 1) br = N - 1;
            GLOAD16(Bw + (size_t)br * K + k0 + ss * 8, Bs + g * 512);
        }
        __syncthreads();
#pragma unroll
        for (int kk = 0; kk < 2; kk++) {
            bf16x8 af[4], bfv[4];
#pragma unroll
            for (int mi = 0; mi < 4; mi++) {
                int row = wr * 64 + mi * 16 + r;
                int boff = row * 128 + (((kk * 4 + ks) ^ (row & 7)) << 4);
                af[mi] = *(const bf16x8*)((const char*)As + boff);
            }
#pragma unroll
            for (int ni = 0; ni < 4; ni++) {
                int row = wc * 64 + ni * 16 + r;
                int boff = row * 128 + (((kk * 4 + ks) ^ (row & 7)) << 4);
                bfv[ni] = *(const bf16x8*)((const char*)Bs + boff);
            }
#pragma unroll
            for (int mi = 0; mi < 4; mi++)
#pragma unroll
                for (int ni = 0; ni < 4; ni++)
                    acc[mi][ni] = __builtin_amdgcn_mfma_f32_16x16x32_bf16(
                        af[mi], bfv[ni], acc[mi][ni], 0, 0, 0);
        }
    }

    int ccol = lane & 15, crow0 = (lane >> 4) * 4;
    if (OUTBF) {
        __syncthreads();
        unsigned short* Cs = smem;
#pragma unroll
        for (int mi = 0; mi < 4; mi++)
#pragma unroll
            for (int ni = 0; ni < 4; ni++) {
                int row = wr * 64 + mi * 16 + crow0;
                int col = wc * 64 + ni * 16 + ccol;
#pragma unroll
                for (int j = 0; j < 4; j++)
                    Cs[(row + j) * CSTR + col] = f2bf(acc[mi][ni][j]);
            }
        __syncthreads();
#pragma unroll
        for (int it = 0; it < 8; it++) {
            int idx = it * 256 + tid;
            int row = idx >> 4, ch = idx & 15;
            uint4 v = *(const uint4*)(Cs + row * CSTR + ch * 8);
            *(uint4*)((unsigned short*)Cout + (size_t)(bm + row) * N + bn + ch * 8) = v;
        }
    } else {
#pragma unroll
        for (int mi = 0; mi < 4; mi++)
#pragma unroll
            for (int ni = 0; ni < 4; ni++) {
                int gc = bn + wc * 64 + ni * 16 + ccol;
                if (gc < N) {
#pragma unroll
                    for (int j = 0; j < 4; j++) {
                        int gr = bm + wr * 64 + mi * 16 + crow0 + j;
                        float v = acc[mi][ni][j];
                        size_t off = (size_t)gr * N + gc;
                        if (RESID) v += resid[off];
                        ((float*)Cout)[off] = v;
                    }
                }
            }
    }
}

// ---------------- depthwise causal conv (K=4) + bias + SiLU ----------------
__global__ __launch_bounds__(256) void k_conv_silu(const unsigned short* __restrict__ proj,
                                                   const float* __restrict__ cw,
                                                   const float* __restrict__ cb,
                                                   unsigned short* __restrict__ u)
{
    __shared__ float sm[11][256];
    int tx = threadIdx.x;
    int t0 = blockIdx.x * 8;
    int i  = blockIdx.y * 256 + tx;
    int b  = blockIdx.z;
#pragma unroll
    for (int r = 0; r < 11; r++) {
        int t = t0 - 3 + r;
        float val = 0.f;
        if (t >= 0) val = bf2f(proj[(size_t)(b * LSEQ + t) * 1024 + i]);
        sm[r][tx] = val;
    }
    __syncthreads();
    float w0 = cw[i * KC + 0], w1 = cw[i * KC + 1], w2 = cw[i * KC + 2], w3 = cw[i * KC + 3];
    float bias = cb[i];
#pragma unroll
    for (int r = 0; r < 8; r++) {
        float s = sm[r][tx] * w0 + sm[r+1][tx] * w1 + sm[r+2][tx] * w2 + sm[r+3][tx] * w3 + bias;
        u[(size_t)(b * LSEQ + t0 + r) * II + i] = f2bf(silu_f(s));
    }
}

// detect A[i,s] == -(s+1) (reference init) -> pow-chain fast path
__device__ __forceinline__ bool a_is_integer(const float* alog, int i) {
    bool fast = true;
#pragma unroll
    for (int s = 0; s < SS; s++)
        fast = fast && (fabsf(expf(alog[i * SS + s]) - (float)(s + 1)) < 1e-3f);
    return fast;
}

// ---------------- slow-path helpers (general A) ----------------
// dp: dt store location (stride 1024, proj hs-half)
__device__ void scanA_slow_one(const float (*sm)[48], const unsigned short* up,
                               unsigned short* dp,
                               const float* wdt, const float* Ac, float bias,
                               float* Pr, float* Sr)
{
#pragma unroll
    for (int s = 0; s < SS; s++) { Pr[s] = 1.f; Sr[s] = 0.f; }
    for (int t = 0; t < LCH; t++) {
        float dacc = bias;
#pragma unroll
        for (int q = 0; q < 4; q++) {
            float4 a = *(const float4*)&sm[t][q * 4];
            dacc = fmaf(a.x, wdt[q*4+0], dacc); dacc = fmaf(a.y, wdt[q*4+1], dacc);
            dacc = fmaf(a.z, wdt[q*4+2], dacc); dacc = fmaf(a.w, wdt[q*4+3], dacc);
        }
        float e   = __expf(-fabsf(dacc));
        float dtv = fmaxf(dacc, 0.f) + __logf(1.f + e);
        dp[(size_t)t * 1024] = f2bf(dtv);
        float uv = bf2f(up[(size_t)t * II]);
        float du = dtv * uv;
#pragma unroll
        for (int q = 0; q < 4; q++) {
            float4 bv = *(const float4*)&sm[t][16 + q * 4];
            float dA0 = __expf(dtv * Ac[q*4+0]), dA1 = __expf(dtv * Ac[q*4+1]);
            float dA2 = __expf(dtv * Ac[q*4+2]), dA3 = __expf(dtv * Ac[q*4+3]);
            Pr[q*4+0] *= dA0; Pr[q*4+1] *= dA1; Pr[q*4+2] *= dA2; Pr[q*4+3] *= dA3;
            Sr[q*4+0] = fmaf(dA0, Sr[q*4+0], du * bv.x);
            Sr[q*4+1] = fmaf(dA1, Sr[q*4+1], du * bv.y);
            Sr[q*4+2] = fmaf(dA2, Sr[q*4+2], du * bv.z);
            Sr[q*4+3] = fmaf(dA3, Sr[q*4+3], du * bv.w);
        }
    }
}

// reads dt from dp (stride 1024), writes y to same slot after use
__device__ void scanC_slow_one(const float (*sm)[48], const unsigned short* up,
                               const unsigned short* gp, unsigned short* dyp,
                               const float* Ac, float Dv, float* st)
{
    for (int t = 0; t < LCH; t++) {
        float dtv = bf2f(dyp[(size_t)t * 1024]);
        float uv = bf2f(up[(size_t)t * II]);
        float du = dtv * uv;
        float acc = 0.f;
#pragma unroll
        for (int q = 0; q < 4; q++) {
            float4 bv = *(const float4*)&sm[t][16 + q * 4];
            float4 cv = *(const float4*)&sm[t][32 + q * 4];
            float dA0 = __expf(dtv * Ac[q*4+0]), dA1 = __expf(dtv * Ac[q*4+1]);
            float dA2 = __expf(dtv * Ac[q*4+2]), dA3 = __expf(dtv * Ac[q*4+3]);
            st[q*4+0] = fmaf(dA0, st[q*4+0], du * bv.x);
            st[q*4+1] = fmaf(dA1, st[q*4+1], du * bv.y);
            st[q*4+2] = fmaf(dA2, st[q*4+2], du * bv.z);
            st[q*4+3] = fmaf(dA3, st[q*4+3], du * bv.w);
            acc = fmaf(st[q*4+0], cv.x, acc); acc = fmaf(st[q*4+1], cv.y, acc);
            acc = fmaf(st[q*4+2], cv.z, acc); acc = fmaf(st[q*4+3], cv.w, acc);
        }
        float yv = acc + uv * Dv;
        float gv = bf2f(gp[(size_t)t * 1024]);
        dyp[(size_t)t * 1024] = f2bf(yv * silu_f(gv));
    }
}

// P/S layout (chunk-major): [c][b][i][s], offset = c*nbis + (b*II+i)*SS + s
// ---------------- scan pass A: 2 chunk-chains; dt -> proj hs-half (bf16) -------
__global__ __launch_bounds__(256) void k_scanA(const float* __restrict__ ssm,
                                               const unsigned short* __restrict__ u,
                                               unsigned short* __restrict__ proj,
                                               const float* __restrict__ dtw,
                                               const float* __restrict__ dtb,
                                               const float* __restrict__ alog,
                                               float* __restrict__ P,
                                               float* __restrict__ S)
{
    __shared__ float sms[2][LCH][48];
    int tid = threadIdx.x;
    int i = blockIdx.x * 256 + tid;
    int c = blockIdx.y;                    // 0..31; chain B = c+32
    int b = blockIdx.z;
    int cB = c + 32;
    bool twoOut = (cB < NCCH - 1);         // chunk 63 P/S output dead (dt still written)
    size_t nbis = (size_t)gridDim.z * II * SS;

    const float* srbA = ssm + ((size_t)b * LSEQ + c * LCH) * 48;
    const float* srbB = ssm + ((size_t)b * LSEQ + cB * LCH) * 48;
    for (int v = tid; v < LCH * 12; v += 256) {
        int t = v / 12, q = v - t * 12;
        *(float4*)&sms[0][t][q * 4] = *(const float4*)(srbA + (size_t)t * 48 + q * 4);
        *(float4*)&sms[1][t][q * 4] = *(const float4*)(srbB + (size_t)t * 48 + q * 4);
    }
    __syncthreads();

    float bias = dtb[i];
    const unsigned short* upA = u + ((size_t)b * LSEQ + c * LCH) * II + i;
    const unsigned short* upB = u + ((size_t)b * LSEQ + cB * LCH) * II + i;
    unsigned short* dpA = proj + ((size_t)b * LSEQ + c * LCH) * 1024 + i;
    unsigned short* dpB = proj + ((size_t)b * LSEQ + cB * LCH) * 1024 + i;
    size_t oA = (size_t)c * nbis + (((size_t)b * II + i) * SS);
    size_t oB = (size_t)cB * nbis + (((size_t)b * II + i) * SS);

    if (a_is_integer(alog, i)) {
        f32x2 wdt2[8];
#pragma unroll
        for (int k = 0; k < 8; k++) wdt2[k] = *(const f32x2*)(dtw + i * RR + k * 2);
        f32x2 SrA[8], SrB[8];
#pragma unroll
        for (int k = 0; k < 8; k++) { SrA[k] = (f32x2){0.f, 0.f}; SrB[k] = (f32x2){0.f, 0.f}; }
        float dtsumA = 0.f, dtsumB = 0.f;
        for (int t = 0; t < LCH; t++) {
            const f32x2* aA = (const f32x2*)&sms[0][t][0];
            const f32x2* aB = (const f32x2*)&sms[1][t][0];
            f32x2 dA2 = (f32x2){bias, 0.f}, dB2 = (f32x2){bias, 0.f};
#pragma unroll
            for (int k = 0; k < 8; k++) {
                dA2 = __builtin_elementwise_fma(aA[k], wdt2[k], dA2);
                dB2 = __builtin_elementwise_fma(aB[k], wdt2[k], dB2);
            }
            float daccA = dA2.x + dA2.y, daccB = dB2.x + dB2.y;
            float eA = __expf(-fabsf(daccA)), eB = __expf(-fabsf(daccB));
            float dtA = fmaxf(daccA, 0.f) + __logf(1.f + eA);
            float dtB = fmaxf(daccB, 0.f) + __logf(1.f + eB);
            dpA[(size_t)t * 1024] = f2bf(dtA);
            dpB[(size_t)t * 1024] = f2bf(dtB);
            float rA = __expf(-dtA), rB = __expf(-dtB);
            dtsumA += dtA; dtsumB += dtB;
            float uvA = bf2f(upA[(size_t)t * II]), uvB = bf2f(upB[(size_t)t * II]);
            float duA = dtA * uvA, duB = dtB * uvB;
            f32x2 duA2 = (f32x2){duA, duA}, duB2 = (f32x2){duB, duB};
            f32x2 pwA[8], pwB[8];
            powtree2(rA, pwA); powtree2(rB, pwB);
            const f32x2* bvA = (const f32x2*)&sms[0][t][16];
            const f32x2* bvB = (const f32x2*)&sms[1][t][16];
#pragma unroll
            for (int k = 0; k < 8; k++) {
                SrA[k] = __builtin_elementwise_fma(pwA[k], SrA[k], duA2 * bvA[k]);
                SrB[k] = __builtin_elementwise_fma(pwB[k], SrB[k], duB2 * bvB[k]);
            }
        }
        f32x2 PrA[8]; powtree2(__expf(-dtsumA), PrA);
#pragma unroll
        for (int k = 0; k < 8; k++) {
            *(f32x2*)(P + oA + k * 2) = PrA[k];
            *(f32x2*)(S + oA + k * 2) = SrA[k];
        }
        if (twoOut) {
            f32x2 PrB[8]; powtree2(__expf(-dtsumB), PrB);
#pragma unroll
            for (int k = 0; k < 8; k++) {
                *(f32x2*)(P + oB + k * 2) = PrB[k];
                *(f32x2*)(S + oB + k * 2) = SrB[k];
            }
        }
    } else {
        float wdt[16];
#pragma unroll
        for (int q = 0; q < 4; q++) *(float4*)&wdt[q*4] = *(const float4*)(dtw + i * RR + q * 4);
        float Ac[SS];
#pragma unroll
        for (int s = 0; s < SS; s++) Ac[s] = -expf(alog[i * SS + s]);
        float Pr[SS], Sr[SS];
        scanA_slow_one(sms[0], upA, dpA, wdt, Ac, bias, Pr, Sr);
#pragma unroll
        for (int q = 0; q < 4; q++) {
            *(float4*)(P + oA + q*4) = make_float4(Pr[q*4], Pr[q*4+1], Pr[q*4+2], Pr[q*4+3]);
            *(float4*)(S + oA + q*4) = make_float4(Sr[q*4], Sr[q*4+1], Sr[q*4+2], Sr[q*4+3]);
        }
        scanA_slow_one(sms[1], upB, dpB, wdt, Ac, bias, Pr, Sr);
        if (twoOut) {
#pragma unroll
            for (int q = 0; q < 4; q++) {
                *(float4*)(P + oB + q*4) = make_float4(Pr[q*4], Pr[q*4+1], Pr[q*4+2], Pr[q*4+3]);
                *(float4*)(S + oB + q*4) = make_float4(Sr[q*4], Sr[q*4+1], Sr[q*4+2], Sr[q*4+3]);
            }
        }
    }
}

// ---------------- scan pass B: per-(b,i,s) scalar carry, coalesced slices ------
__global__ __launch_bounds__(256) void k_scanB(float* __restrict__ P,
                                               const float* __restrict__ S,
                                               int nbis)
{
    int idx = blockIdx.x * 256 + threadIdx.x;
    float carry = 0.f;
#pragma unroll 4
    for (int c = 0; c < NCCH - 1; c++) {
        size_t o = (size_t)c * nbis + idx;
        float Pv = P[o];
        float Sv = S[o];
        float nc = fmaf(Pv, carry, Sv);
        P[o] = carry;
        carry = nc;
    }
    P[(size_t)(NCCH - 1) * nbis + idx] = carry;
}

// ---------------- scan pass C: 2 chunk-chains; dt from proj hs, y over it ------
__global__ __launch_bounds__(256) void k_scanC(const float* __restrict__ ssm,
                                               const unsigned short* __restrict__ u,
                                               const float* __restrict__ alog,
                                               const float* __restrict__ st0,
                                               unsigned short* proj,
                                               const float* __restrict__ Dp)
{
    __shared__ float sms[2][LCH][48];
    int tid = threadIdx.x;
    int i = blockIdx.x * 256 + tid;
    int c = blockIdx.y;                    // 0..31; chain B = c+32
    int b = blockIdx.z;
    int cB = c + 32;
    size_t nbis = (size_t)gridDim.z * II * SS;

    const float* srbA = ssm + ((size_t)b * LSEQ + c * LCH) * 48;
    const float* srbB = ssm + ((size_t)b * LSEQ + cB * LCH) * 48;
    for (int v = tid; v < LCH * 12; v += 256) {
        int t = v / 12, q = v - t * 12;
        *(float4*)&sms[0][t][q * 4] = *(const float4*)(srbA + (size_t)t * 48 + q * 4);
        *(float4*)&sms[1][t][q * 4] = *(const float4*)(srbB + (size_t)t * 48 + q * 4);
    }
    __syncthreads();

    float Dv = Dp[i];
    size_t oA = (size_t)c * nbis + (((size_t)b * II + i) * SS);
    size_t oB = (size_t)cB * nbis + (((size_t)b * II + i) * SS);

    const unsigned short* upA = u + ((size_t)b * LSEQ + c * LCH) * II + i;
    const unsigned short* upB = u + ((size_t)b * LSEQ + cB * LCH) * II + i;
    const unsigned short* gpA = proj + ((size_t)b * LSEQ + c * LCH) * 1024 + 512 + i;
    const unsigned short* gpB = proj + ((size_t)b * LSEQ + cB * LCH) * 1024 + 512 + i;
    unsigned short* dyA = proj + ((size_t)b * LSEQ + c * LCH) * 1024 + i;   // dt in, y out
    unsigned short* dyB = proj + ((size_t)b * LSEQ + cB * LCH) * 1024 + i;

    if (a_is_integer(alog, i)) {
        f32x2 stA[8], stB[8];
#pragma unroll
        for (int k = 0; k < 8; k++) {
            stA[k] = *(const f32x2*)(st0 + oA + k * 2);
            stB[k] = *(const f32x2*)(st0 + oB + k * 2);
        }
        for (int t = 0; t < LCH; t++) {
            float dtA = bf2f(dyA[(size_t)t * 1024]);
            float dtB = bf2f(dyB[(size_t)t * 1024]);
            float rA = __expf(-dtA), rB = __expf(-dtB);
            float uvA = bf2f(upA[(size_t)t * II]), uvB = bf2f(upB[(size_t)t * II]);
            float duA = dtA * uvA, duB = dtB * uvB;
            f32x2 duA2 = (f32x2){duA, duA}, duB2 = (f32x2){duB, duB};
            f32x2 pwA[8], pwB[8];
            powtree2(rA, pwA); powtree2(rB, pwB);
            const f32x2* bvA = (const f32x2*)&sms[0][t][16];
            const f32x2* bvB = (const f32x2*)&sms[1][t][16];
            const f32x2* cvA = (const f32x2*)&sms[0][t][32];
            const f32x2* cvB = (const f32x2*)&sms[1][t][32];
            f32x2 accA = (f32x2){0.f, 0.f}, accB = (f32x2){0.f, 0.f};
#pragma unroll
            for (int k = 0; k < 8; k++) {
                stA[k] = __builtin_elementwise_fma(pwA[k], stA[k], duA2 * bvA[k]);
                stB[k] = __builtin_elementwise_fma(pwB[k], stB[k], duB2 * bvB[k]);
                accA = __builtin_elementwise_fma(stA[k], cvA[k], accA);
                accB = __builtin_elementwise_fma(stB[k], cvB[k], accB);
            }
            float yvA = (accA.x + accA.y) + uvA * Dv;
            float yvB = (accB.x + accB.y) + uvB * Dv;
            float gvA = bf2f(gpA[(size_t)t * 1024]);
            float gvB = bf2f(gpB[(size_t)t * 1024]);
            dyA[(size_t)t * 1024] = f2bf(yvA * silu_f(gvA));
            dyB[(size_t)t * 1024] = f2bf(yvB * silu_f(gvB));
        }
    } else {
        float Ac[SS];
#pragma unroll
        for (int s = 0; s < SS; s++) Ac[s] = -expf(alog[i * SS + s]);
        float st[SS];
#pragma unroll
        for (int q = 0; q < 4; q++) *(float4*)&st[q*4] = *(const float4*)(st0 + oA + q*4);
        scanC_slow_one(sms[0], upA, gpA, dyA, Ac, Dv, st);
#pragma unroll
        for (int q = 0; q < 4; q++) *(float4*)&st[q*4] = *(const float4*)(st0 + oB + q*4);
        scanC_slow_one(sms[1], upB, gpB, dyB, Ac, Dv, st);
    }
}

extern "C" void kernel_launch(void* const* d_in, const int* in_sizes, int n_in,
                              void* d_out, int out_size, void* d_ws, size_t ws_size,
                              hipStream_t stream)
{
    const float* x_in   = (const float*)d_in[0];
    const float* norm_w = (const float*)d_in[1];
    const float* in_w   = (const float*)d_in[2];
    const float* conv_w = (const float*)d_in[3];
    const float* conv_b = (const float*)d_in[4];
    const float* xp_w   = (const float*)d_in[5];
    const float* dt_w   = (const float*)d_in[6];
    const float* dt_b   = (const float*)d_in[7];
    const float* alog   = (const float*)d_in[8];
    const float* Dp     = (const float*)d_in[9];
    const float* out_w  = (const float*)d_in[10];
    float* out = (float*)d_out;   // persistent residual stream (fp32)

    const size_t w_in  = (size_t)NLAY * 2 * II * HID;
    const size_t w_out = (size_t)NLAY * HID * II;
    const size_t w_xp  = (size_t)NLAY * 48 * II;
    const size_t wbytes = (w_in + w_out + w_xp) * 2;

    // per-row floats: ssm 48 + P 256 + S 256 + h_bf 128 + proj_bf 512 + u_bf 256 = 1456
    int Bc = 1;
    for (int cand = BATCH; cand >= 1; cand >>= 1) {
        size_t need = (size_t)cand * LSEQ * 1456 * sizeof(float) + wbytes + (1 << 20);
        if (need <= ws_size) { Bc = cand; break; }
    }
    size_t Mc = (size_t)Bc * LSEQ;
    int ntm = (int)(Mc / 128);
    int nbis = Bc * II * SS;

    float* wsf = (float*)d_ws;
    float*          ssm     = wsf;
    float*          P       = wsf + Mc * 48;
    float*          S       = wsf + Mc * 304;
    unsigned short* h_bf    = (unsigned short*)(wsf + Mc * 560);
    unsigned short* proj_bf = (unsigned short*)(wsf + Mc * 688);   // [Mc,1024]
    unsigned short* u_bf    = (unsigned short*)(wsf + Mc * 1200);
    unsigned short* inw_bf  = (unsigned short*)(wsf + Mc * 1456);
    unsigned short* outw_bf = inw_bf + w_in;
    unsigned short* xpw_bf  = outw_bf + w_out;

    k_f2bf<<<2048, 256, 0, stream>>>(in_w,  inw_bf,  (int)w_in);
    k_f2bf<<<2048, 256, 0, stream>>>(out_w, outw_bf, (int)w_out);
    k_f2bf<<<2048, 256, 0, stream>>>(xp_w,  xpw_bf,  (int)w_xp);

    const int nchunk = BATCH / Bc;

    for (int l = 0; l < NLAY; l++) {
        for (int c = 0; c < nchunk; c++) {
            size_t row0 = (size_t)c * Mc;
            const float* xsrc = (l == 0) ? x_in + row0 * HID : out + row0 * HID;
            float*       dst  = out + row0 * HID;

            k_rmsnorm<<<(int)(Mc / 4), 256, 0, stream>>>(xsrc, norm_w + l * HID, h_bf);
            k_gemm_mfma<0,1><<<ntm * 8, 256, 0, stream>>>(
                h_bf, inw_bf + (size_t)l * 2 * II * HID, nullptr, proj_bf,
                2 * II, HID, HID, 8);
            k_conv_silu<<<dim3(LSEQ / 8, 2, Bc), 256, 0, stream>>>(
                proj_bf, conv_w + (size_t)l * II * KC, conv_b + (size_t)l * II, u_bf);
            k_gemm_mfma<0,0><<<ntm, 256, 0, stream>>>(
                u_bf, xpw_bf + (size_t)l * 48 * II, nullptr, ssm, 48, II, II, 1);
            k_scanA<<<dim3(II / 256, NCCH / 2, Bc), 256, 0, stream>>>(
                ssm, u_bf, proj_bf, dt_w + (size_t)l * II * RR, dt_b + (size_t)l * II,
                alog + (size_t)l * II * SS, P, S);
            k_scanB<<<nbis / 256, 256, 0, stream>>>(P, S, nbis);
            k_scanC<<<dim3(II / 256, NCCH / 2, Bc), 256, 0, stream>>>(
                ssm, u_bf, alog + (size_t)l * II * SS, P, proj_bf, Dp + (size_t)l * II);
            k_gemm_mfma<1,0><<<ntm * 2, 256, 0, stream>>>(
                proj_bf, outw_bf + (size_t)l * HID * II, xsrc, dst, HID, II, 2 * II, 2);
        }
    }
}